// Round 2
// baseline (664.903 us; speedup 1.0000x reference)
//
#include <hip/hip_runtime.h>
#include <stdint.h>

// CCNet criss-cross attention block. B=8, C=256, H=W=128, CR=32.
// detect dtype -> prep weights (bf16 for MFMA, f32 for VALU) -> qkv MFMA GEMM
// (dual-layout bf16 staging) -> MFMA attention x2 (col pass, row pass) ->
// combine+zres.
//
// ws layout (bytes):
//   flag @ 0
//   wb   @ 256      f32[96]   qkv bias
//   wzf  @ 1024     f32[256][32]
//   bzf  @ 33792    f32[256]
//   wbf  @ 34816    bf16[96][256]  qkv weights, n-major (49152 B)
//   qt   @ 147456   bf16 (B,W,H,32) col-major  8 MB
//   kt,vt           +8MB each
//   qr/kr/vr        +24MB..: bf16 (B,H,W,32) row-major
//   Ocol @ 50479104 bf16 (B,H,W,32) 8 MB
//   Orow @ 58867712 bf16 (B,H,W,32) 8 MB
//   scol @ 67256320 f32 (B,H,W) 512 KB
//   srow @ 67780608 f32 (B,H,W) 512 KB

typedef __attribute__((ext_vector_type(8))) short bf16x8;
typedef __attribute__((ext_vector_type(4))) float f32x4;
union frag_u { uint4 u4; bf16x8 h8; };

__device__ __forceinline__ float bf2f(uint32_t u) {
  union { uint32_t i; float f; } v; v.i = u << 16; return v.f;
}
__device__ __forceinline__ float bf2f_hi(uint32_t u) {
  union { uint32_t i; float f; } v; v.i = u & 0xffff0000u; return v.f;
}
__device__ __forceinline__ uint32_t f2bf(float f) {           // RNE
  union { float f; uint32_t i; } v; v.f = f;
  return (v.i + 0x7fffu + ((v.i >> 16) & 1u)) >> 16;
}
__device__ __forceinline__ uint32_t packpair(float lo, float hi) {
  return f2bf(lo) | (f2bf(hi) << 16);
}
__device__ __forceinline__ void unpack8(uint4 a, float* f) {
  f[0] = bf2f(a.x); f[1] = bf2f_hi(a.x);
  f[2] = bf2f(a.y); f[3] = bf2f_hi(a.y);
  f[4] = bf2f(a.z); f[5] = bf2f_hi(a.z);
  f[6] = bf2f(a.w); f[7] = bf2f_hi(a.w);
}
__device__ __forceinline__ float ld_any(const void* p, int i, int isf32) {
  return isf32 ? ((const float*)p)[i] : bf2f(((const uint16_t*)p)[i]);
}

// -------------------------------------------------------------- detect ------
__global__ void detect_kernel(const uint16_t* __restrict__ x, int* __restrict__ flag) {
  __shared__ int bad;
  if (threadIdx.x == 0) bad = 0;
  __syncthreads();
  int hit = 0;
#pragma unroll
  for (int s = 0; s < 16; ++s) {
    uint32_t u = x[(threadIdx.x * 16 + s) * 2];
    uint32_t e = (u >> 7) & 0xffu;
    if (e == 0u || e == 255u) hit = 1;
  }
  if (hit) atomicAdd(&bad, 1);
  __syncthreads();
  if (threadIdx.x == 0) flag[0] = (bad > 0) ? 1 : 0;
}

// ---------------------------------------------------------------- prep ------
__global__ void prep_kernel(
    const int* __restrict__ flag,
    const void* __restrict__ Wq, const void* __restrict__ bq,
    const void* __restrict__ Wk, const void* __restrict__ bk,
    const void* __restrict__ Wv, const void* __restrict__ bv,
    const void* __restrict__ Wz, const void* __restrict__ bz,
    float* __restrict__ wb, float* __restrict__ wzf,
    float* __restrict__ bzf, uint16_t* __restrict__ wbf)
{
  int isf32 = flag[0];
  int t = blockIdx.x * 256 + threadIdx.x;
  if (t < 24576) {                     // wbf[n][k], n = z*32+o
    int n = t >> 8, kk = t & 255;
    int z = n >> 5, o = n & 31;
    const void* W = (z == 0) ? Wq : (z == 1) ? Wk : Wv;
    wbf[t] = (uint16_t)f2bf(ld_any(W, o * 256 + kk, isf32));
  }
  if (t < 96) {
    int z = t >> 5, o = t & 31;
    const void* bb = (z == 0) ? bq : (z == 1) ? bk : bv;
    wb[t] = ld_any(bb, o, isf32);
  }
  if (t < 8192) wzf[t] = ld_any(Wz, t, isf32);
  if (t < 256)  bzf[t] = ld_any(bz, t, isf32);
}

// ------------------------------------------------------------ qkv MFMA ------
// GEMM: out[m][n] = sum_k X[b][k][pix] * W[n][k], block = one (b, hrow) row
// of 128 pixels (m = w), N=96 (q|k|v), K=256 in 8 chunks of 32.
// A-frags from LDS Xs[m][k] (stride 40 elems, 16B-aligned rows), B-frags
// straight from global wbf (L2-broadcast). Frag pattern identical to the
// HW-verified attn kernel (A[m=l15][k=quad*8+j], B[n=l15][k], C/D col=l15,
// row=quad*4+r).
__global__ __launch_bounds__(256) void qkv_mfma(
    const int* __restrict__ flag, const void* __restrict__ x,
    const uint16_t* __restrict__ wbf, const float* __restrict__ wb,
    uint16_t* __restrict__ qcol, uint16_t* __restrict__ kcol,
    uint16_t* __restrict__ vcol, uint16_t* __restrict__ qrow,
    uint16_t* __restrict__ krow, uint16_t* __restrict__ vrow)
{
  __shared__ __align__(16) uint16_t Xs[128 * 40];
  int isf32 = flag[0];
  int bx = blockIdx.x;
  int b = bx >> 7, hrow = bx & 127;
  int t = threadIdx.x;
  int wv = t >> 6, L = t & 63, quad = L >> 4, l15 = L & 15;

  f32x4 acc[2][6];
#pragma unroll
  for (int mi = 0; mi < 2; ++mi)
#pragma unroll
    for (int nt = 0; nt < 6; ++nt) {
      f32x4 z0 = {0.f, 0.f, 0.f, 0.f};
      acc[mi][nt] = z0;
    }

  for (int kc = 0; kc < 8; ++kc) {
    int k0 = kc * 32;
    __syncthreads();
    // full coverage: 128 m x 32 k = 4096 elems, 16 per thread.
    // (round-4 bug: only 1/4 of Xs was written -> stale LDS -> NaN)
    if (isf32) {
      const float* xp = (const float*)x + ((size_t)b << 22)
                      + (size_t)k0 * 16384 + hrow * 128;
#pragma unroll
      for (int r = 0; r < 16; ++r) {
        int idx = r * 256 + t, k = idx >> 7, m = idx & 127;
        Xs[m * 40 + k] = (uint16_t)f2bf(xp[(size_t)k * 16384 + m]);
      }
    } else {
      const uint16_t* xp = (const uint16_t*)x + ((size_t)b << 22)
                         + (size_t)k0 * 16384 + hrow * 128;
#pragma unroll
      for (int r = 0; r < 16; ++r) {
        int idx = r * 256 + t, k = idx >> 7, m = idx & 127;
        Xs[m * 40 + k] = xp[(size_t)k * 16384 + m];
      }
    }
    __syncthreads();

    bf16x8 af[2];
#pragma unroll
    for (int mi = 0; mi < 2; ++mi) {
      frag_u fu;
      fu.u4 = *(const uint4*)(Xs + ((wv * 2 + mi) * 16 + l15) * 40 + quad * 8);
      af[mi] = fu.h8;
    }
#pragma unroll
    for (int nt = 0; nt < 6; ++nt) {
      frag_u bu;
      bu.u4 = *(const uint4*)(wbf + (nt * 16 + l15) * 256 + k0 + quad * 8);
#pragma unroll
      for (int mi = 0; mi < 2; ++mi)
        acc[mi][nt] = __builtin_amdgcn_mfma_f32_16x16x32_bf16(af[mi], bu.h8, acc[mi][nt], 0, 0, 0);
    }
  }

  // epilogue: bias + store both layouts
#pragma unroll
  for (int nt = 0; nt < 6; ++nt) {
    int n = nt * 16 + l15;
    float bias = wb[n];
    int z = nt >> 1;                   // 0,1->q  2,3->k  4,5->v (uniform)
    int no = n & 31;
    uint16_t* colb = (z == 0) ? qcol : (z == 1) ? kcol : vcol;
    uint16_t* rowb = (z == 0) ? qrow : (z == 1) ? krow : vrow;
    size_t rowbase = (size_t)(b * 128 + hrow) * 4096;
#pragma unroll
    for (int mi = 0; mi < 2; ++mi) {
#pragma unroll
      for (int r = 0; r < 4; ++r) {
        int m = (wv * 2 + mi) * 16 + quad * 4 + r;    // = w coordinate
        uint16_t val = (uint16_t)f2bf(acc[mi][nt][r] + bias);
        rowb[rowbase + (size_t)m * 32 + no] = val;
        colb[(size_t)(b * 128 + m) * 4096 + hrow * 32 + no] = val;
      }
    }
  }
}

// ---------------------------------------------------------------- attn ------
// One block per (b, loc): loc=w (iscol=1, diag-masked height pass) or loc=h
// (width pass). S = Q K^T via MFMA; P = exp(S) -> LDS (stride 136); rowsums;
// O = P V with V^T in LDS. (unchanged — HW-verified round 3)
__global__ __launch_bounds__(256) void attn_kernel(
    const uint16_t* __restrict__ q, const uint16_t* __restrict__ k,
    const uint16_t* __restrict__ v, uint16_t* __restrict__ O,
    float* __restrict__ s, int iscol)
{
  __shared__ __align__(16) uint16_t P[128 * 136];
  __shared__ __align__(16) uint16_t vT[32 * 136];

  int cid = blockIdx.x, b = cid >> 7, loc = cid & 127;
  int tid = threadIdx.x;
  const uint16_t* qc = q + (size_t)cid * 4096;
  const uint16_t* kc = k + (size_t)cid * 4096;
  const uint16_t* vc = v + (size_t)cid * 4096;

  for (int idx = tid; idx < 4096; idx += 256)
    vT[(idx & 31) * 136 + (idx >> 5)] = vc[idx];

  int wv = tid >> 6, L = tid & 63, quad = L >> 4, l15 = L & 15;

  bf16x8 aq[2];
#pragma unroll
  for (int mi = 0; mi < 2; ++mi) {
    frag_u fu;
    fu.u4 = *(const uint4*)(qc + ((wv * 2 + mi) * 16 + l15) * 32 + quad * 8);
    aq[mi] = fu.h8;
  }
  for (int nt = 0; nt < 8; ++nt) {
    frag_u bu;
    bu.u4 = *(const uint4*)(kc + (nt * 16 + l15) * 32 + quad * 8);
    int col = nt * 16 + l15;
#pragma unroll
    for (int mi = 0; mi < 2; ++mi) {
      f32x4 z0 = {0.f, 0.f, 0.f, 0.f};
      f32x4 d = __builtin_amdgcn_mfma_f32_16x16x32_bf16(aq[mi], bu.h8, z0, 0, 0, 0);
      int row0 = (wv * 2 + mi) * 16 + quad * 4;
#pragma unroll
      for (int r = 0; r < 4; ++r) {
        float pe = __expf(d[r]);                 // max-free: |S| <~ 21
        if (iscol && (row0 + r) == col) pe = 0.f;
        P[(row0 + r) * 136 + col] = (uint16_t)f2bf(pe);
      }
    }
  }
  __syncthreads();

  if (tid < 128) {
    float ss = 0.f;
    for (int j = 0; j < 128; ++j) ss += bf2f(P[tid * 136 + j]);
    size_t sbase = (size_t)b * 16384 + (iscol ? loc : loc * 128);
    s[sbase + (size_t)tid * (iscol ? 128 : 1)] = ss;
  }

  f32x4 acc[2][2];
#pragma unroll
  for (int mi = 0; mi < 2; ++mi)
#pragma unroll
    for (int ni = 0; ni < 2; ++ni) {
      f32x4 z0 = {0.f, 0.f, 0.f, 0.f};
      acc[mi][ni] = z0;
    }
#pragma unroll
  for (int kk = 0; kk < 4; ++kk) {
    bf16x8 ap[2], bv2[2];
#pragma unroll
    for (int mi = 0; mi < 2; ++mi) {
      frag_u fu;
      fu.u4 = *(const uint4*)(P + ((wv * 2 + mi) * 16 + l15) * 136 + kk * 32 + quad * 8);
      ap[mi] = fu.h8;
    }
#pragma unroll
    for (int ni = 0; ni < 2; ++ni) {
      frag_u fu;
      fu.u4 = *(const uint4*)(vT + (ni * 16 + l15) * 136 + kk * 32 + quad * 8);
      bv2[ni] = fu.h8;
    }
#pragma unroll
    for (int mi = 0; mi < 2; ++mi)
#pragma unroll
      for (int ni = 0; ni < 2; ++ni)
        acc[mi][ni] = __builtin_amdgcn_mfma_f32_16x16x32_bf16(ap[mi], bv2[ni], acc[mi][ni], 0, 0, 0);
  }

  size_t obase = (size_t)b * 524288 + (size_t)(iscol ? loc * 32 : loc * 4096);
  int orstride = iscol ? 4096 : 32;
#pragma unroll
  for (int mi = 0; mi < 2; ++mi)
#pragma unroll
    for (int ni = 0; ni < 2; ++ni) {
      int col = ni * 16 + l15;
#pragma unroll
      for (int r = 0; r < 4; ++r) {
        int row = (wv * 2 + mi) * 16 + quad * 4 + r;
        O[obase + (size_t)row * orstride + col] = (uint16_t)f2bf(acc[mi][ni][r]);
      }
    }
}

// ------------------------------------------------------- combine + zres -----
// R1 result: CSPLIT=4 took 97->83us but VALUBusy stuck at 23%, HBM 45%:
// store-retirement serialization (unroll-2 = only 2 stores in flight; compiler
// waits vmcnt before recycling store-data VGPRs; 160 cyc VALU vs ~600 cyc
// round-trip = 24% busy, matches). Also FETCH rose +26MB: cgrp=bid&3 put the
// 4 sibling blocks on 4 DIFFERENT XCDs (bid%8 = XCD) -> 4x L2-private O
// copies. R2: (a) remap pixblk=bid&511, cgrp=bid>>9 so siblings are 512 apart
// == same XCD, all co-resident (grid==capacity); (b) explicit c-loop unroll x4
// with 2-partial chains: 4 loads + 4 stores in flight. VGPR budget ~60 (<64
// keeps 8 waves/SIMD).
#define CSPLIT 4
__global__ __launch_bounds__(256) void combine_zres(
    const int* __restrict__ flag, const void* __restrict__ x,
    const uint16_t* __restrict__ Ocol, const uint16_t* __restrict__ Orow,
    const float* __restrict__ scol, const float* __restrict__ srow,
    const float* __restrict__ wzf, const float* __restrict__ bzf,
    void* __restrict__ out)
{
  int isf32 = flag[0];
  int bid = blockIdx.x;
  int pixblk = bid & 511;              // adjacent bids = different pixels
  int cgrp = bid >> 9;                 // siblings 512 apart -> same XCD L2
  int p = pixblk * 256 + threadIdx.x;
  int b = p >> 14;
  int rem = p & 16383;

  float inv = 1.0f / (scol[p] + srow[p]);
  float of[32];
  const uint4* c4 = (const uint4*)(Ocol + (size_t)p * 32);
  const uint4* r4 = (const uint4*)(Orow + (size_t)p * 32);
#pragma unroll
  for (int g = 0; g < 4; ++g) {
    float a[8], bb[8];
    unpack8(c4[g], a);
    unpack8(r4[g], bb);
#pragma unroll
    for (int j = 0; j < 8; ++j) of[g * 8 + j] = (a[j] + bb[j]) * inv;
  }

  int c0 = cgrp * (256 / CSPLIT);

  if (isf32) {
    const float* xp = (const float*)x + ((size_t)b << 22) + rem;
    float* op = (float*)out + ((size_t)b << 22) + rem;
    for (int cc = 0; cc < 256 / CSPLIT; cc += 4) {
      int c = c0 + cc;
      // 4 x-loads issued together (independent of FMA chains below)
      float xv0 = xp[(size_t)(c + 0) << 14];
      float xv1 = xp[(size_t)(c + 1) << 14];
      float xv2 = xp[(size_t)(c + 2) << 14];
      float xv3 = xp[(size_t)(c + 3) << 14];
      const float* w0 = wzf + (c + 0) * 32;
      const float* w1 = wzf + (c + 1) * 32;
      const float* w2 = wzf + (c + 2) * 32;
      const float* w3 = wzf + (c + 3) * 32;
      float a00 = 0.f, a01 = 0.f, a10 = 0.f, a11 = 0.f;
      float a20 = 0.f, a21 = 0.f, a30 = 0.f, a31 = 0.f;
#pragma unroll
      for (int r = 0; r < 16; ++r) {
        a00 += w0[r] * of[r];  a01 += w0[16 + r] * of[16 + r];
        a10 += w1[r] * of[r];  a11 += w1[16 + r] * of[16 + r];
        a20 += w2[r] * of[r];  a21 += w2[16 + r] * of[16 + r];
        a30 += w3[r] * of[r];  a31 += w3[16 + r] * of[16 + r];
      }
      op[(size_t)(c + 0) << 14] = bzf[c + 0] + a00 + a01 + xv0;
      op[(size_t)(c + 1) << 14] = bzf[c + 1] + a10 + a11 + xv1;
      op[(size_t)(c + 2) << 14] = bzf[c + 2] + a20 + a21 + xv2;
      op[(size_t)(c + 3) << 14] = bzf[c + 3] + a30 + a31 + xv3;
    }
  } else {
    const uint16_t* xp = (const uint16_t*)x + ((size_t)b << 22) + rem;
    uint16_t* op = (uint16_t*)out + ((size_t)b << 22) + rem;
    for (int cc = 0; cc < 256 / CSPLIT; cc += 4) {
      int c = c0 + cc;
      float xv0 = bf2f(xp[(size_t)(c + 0) << 14]);
      float xv1 = bf2f(xp[(size_t)(c + 1) << 14]);
      float xv2 = bf2f(xp[(size_t)(c + 2) << 14]);
      float xv3 = bf2f(xp[(size_t)(c + 3) << 14]);
      const float* w0 = wzf + (c + 0) * 32;
      const float* w1 = wzf + (c + 1) * 32;
      const float* w2 = wzf + (c + 2) * 32;
      const float* w3 = wzf + (c + 3) * 32;
      float a00 = 0.f, a01 = 0.f, a10 = 0.f, a11 = 0.f;
      float a20 = 0.f, a21 = 0.f, a30 = 0.f, a31 = 0.f;
#pragma unroll
      for (int r = 0; r < 16; ++r) {
        a00 += w0[r] * of[r];  a01 += w0[16 + r] * of[16 + r];
        a10 += w1[r] * of[r];  a11 += w1[16 + r] * of[16 + r];
        a20 += w2[r] * of[r];  a21 += w2[16 + r] * of[16 + r];
        a30 += w3[r] * of[r];  a31 += w3[16 + r] * of[16 + r];
      }
      op[(size_t)(c + 0) << 14] = (uint16_t)f2bf(bzf[c + 0] + a00 + a01 + xv0);
      op[(size_t)(c + 1) << 14] = (uint16_t)f2bf(bzf[c + 1] + a10 + a11 + xv1);
      op[(size_t)(c + 2) << 14] = (uint16_t)f2bf(bzf[c + 2] + a20 + a21 + xv2);
      op[(size_t)(c + 3) << 14] = (uint16_t)f2bf(bzf[c + 3] + a30 + a31 + xv3);
    }
  }
}

// -------------------------------------------------------------- launch ------
extern "C" void kernel_launch(void* const* d_in, const int* in_sizes, int n_in,
                              void* d_out, int out_size, void* d_ws, size_t ws_size,
                              hipStream_t stream) {
  char* ws = (char*)d_ws;
  int*   flag = (int*)(ws);
  float* wb   = (float*)(ws + 256);
  float* wzf  = (float*)(ws + 1024);
  float* bzf  = (float*)(ws + 33792);
  uint16_t* wbf = (uint16_t*)(ws + 34816);
  uint16_t* qt = (uint16_t*)(ws + 147456);
  uint16_t* kt = qt + 4194304;
  uint16_t* vt = kt + 4194304;
  uint16_t* qr = vt + 4194304;
  uint16_t* kr = qr + 4194304;
  uint16_t* vr = kr + 4194304;
  uint16_t* Ocol = (uint16_t*)(ws + 50479104);
  uint16_t* Orow = (uint16_t*)(ws + 58867712);
  float* scol = (float*)(ws + 67256320);
  float* srow = (float*)(ws + 67780608);

  detect_kernel<<<1, 256, 0, stream>>>((const uint16_t*)d_in[0], flag);
  prep_kernel<<<96, 256, 0, stream>>>(flag, d_in[1], d_in[2], d_in[3], d_in[4],
                                      d_in[5], d_in[6], d_in[7], d_in[8],
                                      wb, wzf, bzf, wbf);
  qkv_mfma<<<1024, 256, 0, stream>>>(flag, d_in[0], wbf, wb,
                                     qt, kt, vt, qr, kr, vr);
  attn_kernel<<<1024, 256, 0, stream>>>(qt, kt, vt, Ocol, scol, 1);
  attn_kernel<<<1024, 256, 0, stream>>>(qr, kr, vr, Orow, srow, 0);
  combine_zres<<<512 * CSPLIT, 256, 0, stream>>>(flag, d_in[0], Ocol, Orow,
                                                 scol, srow, wzf, bzf, d_out);
}

// Round 3
// 348.062 us; speedup vs baseline: 1.9103x; 1.9103x over previous
//
#include <hip/hip_runtime.h>
#include <stdint.h>

// CCNet criss-cross attention block. B=8, C=256, H=W=128, CR=32.
// detect dtype -> prep weights (bf16 for MFMA, f32 for VALU) -> qkv MFMA GEMM
// (dual-layout bf16 staging) -> MFMA attention x2 (col pass, row pass) ->
// combine+zres.
//
// ws layout (bytes):
//   flag @ 0
//   wb   @ 256      f32[96]   qkv bias
//   wzf  @ 1024     f32[256][32]
//   bzf  @ 33792    f32[256]
//   wbf  @ 34816    bf16[96][256]  qkv weights, n-major (49152 B)
//   qt   @ 147456   bf16 (B,W,H,32) col-major  8 MB
//   kt,vt           +8MB each
//   qr/kr/vr        +24MB..: bf16 (B,H,W,32) row-major
//   Ocol @ 50479104 bf16 (B,H,W,32) 8 MB
//   Orow @ 58867712 bf16 (B,H,W,32) 8 MB
//   scol @ 67256320 f32 (B,H,W) 512 KB
//   srow @ 67780608 f32 (B,H,W) 512 KB

typedef __attribute__((ext_vector_type(8))) short bf16x8;
typedef __attribute__((ext_vector_type(4))) float f32x4;
union frag_u { uint4 u4; bf16x8 h8; };

__device__ __forceinline__ float bf2f(uint32_t u) {
  union { uint32_t i; float f; } v; v.i = u << 16; return v.f;
}
__device__ __forceinline__ float bf2f_hi(uint32_t u) {
  union { uint32_t i; float f; } v; v.i = u & 0xffff0000u; return v.f;
}
__device__ __forceinline__ uint32_t f2bf(float f) {           // RNE
  union { float f; uint32_t i; } v; v.f = f;
  return (v.i + 0x7fffu + ((v.i >> 16) & 1u)) >> 16;
}
__device__ __forceinline__ uint32_t packpair(float lo, float hi) {
  return f2bf(lo) | (f2bf(hi) << 16);
}
__device__ __forceinline__ void unpack8(uint4 a, float* f) {
  f[0] = bf2f(a.x); f[1] = bf2f_hi(a.x);
  f[2] = bf2f(a.y); f[3] = bf2f_hi(a.y);
  f[4] = bf2f(a.z); f[5] = bf2f_hi(a.z);
  f[6] = bf2f(a.w); f[7] = bf2f_hi(a.w);
}
__device__ __forceinline__ float ld_any(const void* p, int i, int isf32) {
  return isf32 ? ((const float*)p)[i] : bf2f(((const uint16_t*)p)[i]);
}

// -------------------------------------------------------------- detect ------
__global__ void detect_kernel(const uint16_t* __restrict__ x, int* __restrict__ flag) {
  __shared__ int bad;
  if (threadIdx.x == 0) bad = 0;
  __syncthreads();
  int hit = 0;
#pragma unroll
  for (int s = 0; s < 16; ++s) {
    uint32_t u = x[(threadIdx.x * 16 + s) * 2];
    uint32_t e = (u >> 7) & 0xffu;
    if (e == 0u || e == 255u) hit = 1;
  }
  if (hit) atomicAdd(&bad, 1);
  __syncthreads();
  if (threadIdx.x == 0) flag[0] = (bad > 0) ? 1 : 0;
}

// ---------------------------------------------------------------- prep ------
__global__ void prep_kernel(
    const int* __restrict__ flag,
    const void* __restrict__ Wq, const void* __restrict__ bq,
    const void* __restrict__ Wk, const void* __restrict__ bk,
    const void* __restrict__ Wv, const void* __restrict__ bv,
    const void* __restrict__ Wz, const void* __restrict__ bz,
    float* __restrict__ wb, float* __restrict__ wzf,
    float* __restrict__ bzf, uint16_t* __restrict__ wbf)
{
  int isf32 = flag[0];
  int t = blockIdx.x * 256 + threadIdx.x;
  if (t < 24576) {                     // wbf[n][k], n = z*32+o
    int n = t >> 8, kk = t & 255;
    int z = n >> 5, o = n & 31;
    const void* W = (z == 0) ? Wq : (z == 1) ? Wk : Wv;
    wbf[t] = (uint16_t)f2bf(ld_any(W, o * 256 + kk, isf32));
  }
  if (t < 96) {
    int z = t >> 5, o = t & 31;
    const void* bb = (z == 0) ? bq : (z == 1) ? bk : bv;
    wb[t] = ld_any(bb, o, isf32);
  }
  if (t < 8192) wzf[t] = ld_any(Wz, t, isf32);
  if (t < 256)  bzf[t] = ld_any(bz, t, isf32);
}

// ------------------------------------------------------------ qkv MFMA ------
// GEMM: out[m][n] = sum_k X[b][k][pix] * W[n][k], block = one (b, hrow) row
// of 128 pixels (m = w), N=96 (q|k|v), K=256 in 8 chunks of 32.
// A-frags from LDS Xs[m][k] (stride 40 elems, 16B-aligned rows), B-frags
// straight from global wbf (L2-broadcast). Frag pattern identical to the
// HW-verified attn kernel (A[m=l15][k=quad*8+j], B[n=l15][k], C/D col=l15,
// row=quad*4+r).
__global__ __launch_bounds__(256) void qkv_mfma(
    const int* __restrict__ flag, const void* __restrict__ x,
    const uint16_t* __restrict__ wbf, const float* __restrict__ wb,
    uint16_t* __restrict__ qcol, uint16_t* __restrict__ kcol,
    uint16_t* __restrict__ vcol, uint16_t* __restrict__ qrow,
    uint16_t* __restrict__ krow, uint16_t* __restrict__ vrow)
{
  __shared__ __align__(16) uint16_t Xs[128 * 40];
  int isf32 = flag[0];
  int bx = blockIdx.x;
  int b = bx >> 7, hrow = bx & 127;
  int t = threadIdx.x;
  int wv = t >> 6, L = t & 63, quad = L >> 4, l15 = L & 15;

  f32x4 acc[2][6];
#pragma unroll
  for (int mi = 0; mi < 2; ++mi)
#pragma unroll
    for (int nt = 0; nt < 6; ++nt) {
      f32x4 z0 = {0.f, 0.f, 0.f, 0.f};
      acc[mi][nt] = z0;
    }

  for (int kc = 0; kc < 8; ++kc) {
    int k0 = kc * 32;
    __syncthreads();
    // full coverage: 128 m x 32 k = 4096 elems, 16 per thread.
    // (round-4 bug: only 1/4 of Xs was written -> stale LDS -> NaN)
    if (isf32) {
      const float* xp = (const float*)x + ((size_t)b << 22)
                      + (size_t)k0 * 16384 + hrow * 128;
#pragma unroll
      for (int r = 0; r < 16; ++r) {
        int idx = r * 256 + t, k = idx >> 7, m = idx & 127;
        Xs[m * 40 + k] = (uint16_t)f2bf(xp[(size_t)k * 16384 + m]);
      }
    } else {
      const uint16_t* xp = (const uint16_t*)x + ((size_t)b << 22)
                         + (size_t)k0 * 16384 + hrow * 128;
#pragma unroll
      for (int r = 0; r < 16; ++r) {
        int idx = r * 256 + t, k = idx >> 7, m = idx & 127;
        Xs[m * 40 + k] = xp[(size_t)k * 16384 + m];
      }
    }
    __syncthreads();

    bf16x8 af[2];
#pragma unroll
    for (int mi = 0; mi < 2; ++mi) {
      frag_u fu;
      fu.u4 = *(const uint4*)(Xs + ((wv * 2 + mi) * 16 + l15) * 40 + quad * 8);
      af[mi] = fu.h8;
    }
#pragma unroll
    for (int nt = 0; nt < 6; ++nt) {
      frag_u bu;
      bu.u4 = *(const uint4*)(wbf + (nt * 16 + l15) * 256 + k0 + quad * 8);
#pragma unroll
      for (int mi = 0; mi < 2; ++mi)
        acc[mi][nt] = __builtin_amdgcn_mfma_f32_16x16x32_bf16(af[mi], bu.h8, acc[mi][nt], 0, 0, 0);
    }
  }

  // epilogue: bias + store both layouts
#pragma unroll
  for (int nt = 0; nt < 6; ++nt) {
    int n = nt * 16 + l15;
    float bias = wb[n];
    int z = nt >> 1;                   // 0,1->q  2,3->k  4,5->v (uniform)
    int no = n & 31;
    uint16_t* colb = (z == 0) ? qcol : (z == 1) ? kcol : vcol;
    uint16_t* rowb = (z == 0) ? qrow : (z == 1) ? krow : vrow;
    size_t rowbase = (size_t)(b * 128 + hrow) * 4096;
#pragma unroll
    for (int mi = 0; mi < 2; ++mi) {
#pragma unroll
      for (int r = 0; r < 4; ++r) {
        int m = (wv * 2 + mi) * 16 + quad * 4 + r;    // = w coordinate
        uint16_t val = (uint16_t)f2bf(acc[mi][nt][r] + bias);
        rowb[rowbase + (size_t)m * 32 + no] = val;
        colb[(size_t)(b * 128 + m) * 4096 + hrow * 32 + no] = val;
      }
    }
  }
}

// ---------------------------------------------------------------- attn ------
// One block per (b, loc): loc=w (iscol=1, diag-masked height pass) or loc=h
// (width pass). S = Q K^T via MFMA; P = exp(S) -> LDS (stride 136); rowsums;
// O = P V with V^T in LDS.
// R3: (a) all 8 K-frags hoisted into bu[8] — one L3 latency instead of 8
// serial exposures in the nt loop (occupancy is LDS-capped at 3 blocks/CU,
// so +32 VGPR is free); (b) rowsum reads ds_read_b64 (uint2, 4 elems/read,
// same summation order -> bit-identical) instead of 128 scalar ds_read_u16.
__global__ __launch_bounds__(256) void attn_kernel(
    const uint16_t* __restrict__ q, const uint16_t* __restrict__ k,
    const uint16_t* __restrict__ v, uint16_t* __restrict__ O,
    float* __restrict__ s, int iscol)
{
  __shared__ __align__(16) uint16_t P[128 * 136];
  __shared__ __align__(16) uint16_t vT[32 * 136];

  int cid = blockIdx.x, b = cid >> 7, loc = cid & 127;
  int tid = threadIdx.x;
  const uint16_t* qc = q + (size_t)cid * 4096;
  const uint16_t* kc = k + (size_t)cid * 4096;
  const uint16_t* vc = v + (size_t)cid * 4096;

  for (int idx = tid; idx < 4096; idx += 256)
    vT[(idx & 31) * 136 + (idx >> 5)] = vc[idx];

  int wv = tid >> 6, L = tid & 63, quad = L >> 4, l15 = L & 15;

  bf16x8 aq[2];
#pragma unroll
  for (int mi = 0; mi < 2; ++mi) {
    frag_u fu;
    fu.u4 = *(const uint4*)(qc + ((wv * 2 + mi) * 16 + l15) * 32 + quad * 8);
    aq[mi] = fu.h8;
  }
  // hoisted K-fragments: 8 independent loads issue back-to-back
  frag_u bu[8];
#pragma unroll
  for (int nt = 0; nt < 8; ++nt)
    bu[nt].u4 = *(const uint4*)(kc + (nt * 16 + l15) * 32 + quad * 8);

#pragma unroll
  for (int nt = 0; nt < 8; ++nt) {
    int col = nt * 16 + l15;
#pragma unroll
    for (int mi = 0; mi < 2; ++mi) {
      f32x4 z0 = {0.f, 0.f, 0.f, 0.f};
      f32x4 d = __builtin_amdgcn_mfma_f32_16x16x32_bf16(aq[mi], bu[nt].h8, z0, 0, 0, 0);
      int row0 = (wv * 2 + mi) * 16 + quad * 4;
#pragma unroll
      for (int r = 0; r < 4; ++r) {
        float pe = __expf(d[r]);                 // max-free: |S| <~ 21
        if (iscol && (row0 + r) == col) pe = 0.f;
        P[(row0 + r) * 136 + col] = (uint16_t)f2bf(pe);
      }
    }
  }
  __syncthreads();

  if (tid < 128) {
    float ss = 0.f;
    const uint2* prow = (const uint2*)(P + tid * 136);   // 272B row, 8B aligned
#pragma unroll 4
    for (int j = 0; j < 32; ++j) {
      uint2 u = prow[j];
      ss += bf2f(u.x); ss += bf2f_hi(u.x);
      ss += bf2f(u.y); ss += bf2f_hi(u.y);
    }
    size_t sbase = (size_t)b * 16384 + (iscol ? loc : loc * 128);
    s[sbase + (size_t)tid * (iscol ? 128 : 1)] = ss;
  }

  f32x4 acc[2][2];
#pragma unroll
  for (int mi = 0; mi < 2; ++mi)
#pragma unroll
    for (int ni = 0; ni < 2; ++ni) {
      f32x4 z0 = {0.f, 0.f, 0.f, 0.f};
      acc[mi][ni] = z0;
    }
#pragma unroll
  for (int kk = 0; kk < 4; ++kk) {
    bf16x8 ap[2], bv2[2];
#pragma unroll
    for (int mi = 0; mi < 2; ++mi) {
      frag_u fu;
      fu.u4 = *(const uint4*)(P + ((wv * 2 + mi) * 16 + l15) * 136 + kk * 32 + quad * 8);
      ap[mi] = fu.h8;
    }
#pragma unroll
    for (int ni = 0; ni < 2; ++ni) {
      frag_u fu;
      fu.u4 = *(const uint4*)(vT + (ni * 16 + l15) * 136 + kk * 32 + quad * 8);
      bv2[ni] = fu.h8;
    }
#pragma unroll
    for (int mi = 0; mi < 2; ++mi)
#pragma unroll
      for (int ni = 0; ni < 2; ++ni)
        acc[mi][ni] = __builtin_amdgcn_mfma_f32_16x16x32_bf16(ap[mi], bv2[ni], acc[mi][ni], 0, 0, 0);
  }

  size_t obase = (size_t)b * 524288 + (size_t)(iscol ? loc * 32 : loc * 4096);
  int orstride = iscol ? 4096 : 32;
#pragma unroll
  for (int mi = 0; mi < 2; ++mi)
#pragma unroll
    for (int ni = 0; ni < 2; ++ni) {
      int col = ni * 16 + l15;
#pragma unroll
      for (int r = 0; r < 4; ++r) {
        int row = (wv * 2 + mi) * 16 + quad * 4 + r;
        O[obase + (size_t)row * orstride + col] = (uint16_t)f2bf(acc[mi][ni][r]);
      }
    }
}

// ------------------------------------------------------- combine + zres -----
// R2 post-mortem: manual 4-channel interleave (8 live accs + 4 weight streams
// + of[32] live across r<16) blew live ranges -> VGPR<->AGPR spill storm
// (v_accvgpr_* are VALU: VALUBusy 90%, dur 402us). REVERTED to the R1 body
// (verified 83us, 40 VGPR, no spills). Kept from R2 (independently verified):
// XCD-coherent remap pixblk=bid&511 / cgrp=bid>>9 — sibling channel-group
// blocks land on the SAME XCD (bid%8 = XCD), deduping O/s re-reads in L2
// (FETCH 100.7 -> 92.2 MB).
#define CSPLIT 4
__global__ __launch_bounds__(256) void combine_zres(
    const int* __restrict__ flag, const void* __restrict__ x,
    const uint16_t* __restrict__ Ocol, const uint16_t* __restrict__ Orow,
    const float* __restrict__ scol, const float* __restrict__ srow,
    const float* __restrict__ wzf, const float* __restrict__ bzf,
    void* __restrict__ out)
{
  int isf32 = flag[0];
  int bid = blockIdx.x;
  int pixblk = bid & 511;              // adjacent bids = different pixels
  int cgrp = bid >> 9;                 // siblings 512 apart -> same XCD L2
  int p = pixblk * 256 + threadIdx.x;
  int b = p >> 14;
  int rem = p & 16383;

  float inv = 1.0f / (scol[p] + srow[p]);
  float of[32];
  const uint4* c4 = (const uint4*)(Ocol + (size_t)p * 32);
  const uint4* r4 = (const uint4*)(Orow + (size_t)p * 32);
#pragma unroll
  for (int g = 0; g < 4; ++g) {
    float a[8], bb[8];
    unpack8(c4[g], a);
    unpack8(r4[g], bb);
#pragma unroll
    for (int j = 0; j < 8; ++j) of[g * 8 + j] = (a[j] + bb[j]) * inv;
  }

  int c0 = cgrp * (256 / CSPLIT);
  int c1 = c0 + (256 / CSPLIT);

  if (isf32) {
    const float* xp = (const float*)x + ((size_t)b << 22) + rem;
    float* op = (float*)out + ((size_t)b << 22) + rem;
#pragma unroll 2
    for (int c = c0; c < c1; ++c) {
      const float* wc = wzf + c * 32;
      float xv = xp[(size_t)c << 14];
      float a0 = 0.f, a1 = 0.f, a2 = 0.f, a3 = 0.f;
#pragma unroll
      for (int r = 0; r < 8; ++r) {
        a0 += wc[r]      * of[r];
        a1 += wc[8 + r]  * of[8 + r];
        a2 += wc[16 + r] * of[16 + r];
        a3 += wc[24 + r] * of[24 + r];
      }
      op[(size_t)c << 14] = bzf[c] + (a0 + a1) + (a2 + a3) + xv;
    }
  } else {
    const uint16_t* xp = (const uint16_t*)x + ((size_t)b << 22) + rem;
    uint16_t* op = (uint16_t*)out + ((size_t)b << 22) + rem;
#pragma unroll 2
    for (int c = c0; c < c1; ++c) {
      const float* wc = wzf + c * 32;
      float xv = bf2f(xp[(size_t)c << 14]);
      float a0 = 0.f, a1 = 0.f, a2 = 0.f, a3 = 0.f;
#pragma unroll
      for (int r = 0; r < 8; ++r) {
        a0 += wc[r]      * of[r];
        a1 += wc[8 + r]  * of[8 + r];
        a2 += wc[16 + r] * of[16 + r];
        a3 += wc[24 + r] * of[24 + r];
      }
      float acci = bzf[c] + (a0 + a1) + (a2 + a3) + xv;
      op[(size_t)c << 14] = (uint16_t)f2bf(acci);
    }
  }
}

// -------------------------------------------------------------- launch ------
extern "C" void kernel_launch(void* const* d_in, const int* in_sizes, int n_in,
                              void* d_out, int out_size, void* d_ws, size_t ws_size,
                              hipStream_t stream) {
  char* ws = (char*)d_ws;
  int*   flag = (int*)(ws);
  float* wb   = (float*)(ws + 256);
  float* wzf  = (float*)(ws + 1024);
  float* bzf  = (float*)(ws + 33792);
  uint16_t* wbf = (uint16_t*)(ws + 34816);
  uint16_t* qt = (uint16_t*)(ws + 147456);
  uint16_t* kt = qt + 4194304;
  uint16_t* vt = kt + 4194304;
  uint16_t* qr = vt + 4194304;
  uint16_t* kr = qr + 4194304;
  uint16_t* vr = kr + 4194304;
  uint16_t* Ocol = (uint16_t*)(ws + 50479104);
  uint16_t* Orow = (uint16_t*)(ws + 58867712);
  float* scol = (float*)(ws + 67256320);
  float* srow = (float*)(ws + 67780608);

  detect_kernel<<<1, 256, 0, stream>>>((const uint16_t*)d_in[0], flag);
  prep_kernel<<<96, 256, 0, stream>>>(flag, d_in[1], d_in[2], d_in[3], d_in[4],
                                      d_in[5], d_in[6], d_in[7], d_in[8],
                                      wb, wzf, bzf, wbf);
  qkv_mfma<<<1024, 256, 0, stream>>>(flag, d_in[0], wbf, wb,
                                     qt, kt, vt, qr, kr, vr);
  attn_kernel<<<1024, 256, 0, stream>>>(qt, kt, vt, Ocol, scol, 1);
  attn_kernel<<<1024, 256, 0, stream>>>(qr, kr, vr, Orow, srow, 0);
  combine_zres<<<512 * CSPLIT, 256, 0, stream>>>(flag, d_in[0], Ocol, Orow,
                                                 scol, srow, wzf, bzf, d_out);
}

// Round 5
// 345.094 us; speedup vs baseline: 1.9267x; 1.0086x over previous
//
#include <hip/hip_runtime.h>
#include <stdint.h>

// CCNet criss-cross attention block. B=8, C=256, H=W=128, CR=32.
// detect dtype -> prep weights (bf16 for MFMA, f32 for VALU) -> qkv MFMA GEMM
// (dual-layout bf16 staging) -> MFMA attention x2 (col pass, row pass) ->
// combine+zres.
//
// ws layout (bytes):
//   flag @ 0
//   wb   @ 256      f32[96]   qkv bias
//   wzf  @ 1024     f32[256][32]
//   bzf  @ 33792    f32[256]
//   wbf  @ 34816    bf16[96][256]  qkv weights, n-major (49152 B)
//   qt   @ 147456   bf16 (B,W,H,32) col-major  8 MB
//   kt,vt           +8MB each
//   qr/kr/vr        +24MB..: bf16 (B,H,W,32) row-major
//   Ocol @ 50479104 bf16 (B,H,W,32) 8 MB
//   Orow @ 58867712 bf16 (B,H,W,32) 8 MB
//   scol @ 67256320 f32 (B,H,W) 512 KB
//   srow @ 67780608 f32 (B,H,W) 512 KB
//
// R4 bench was an infra failure ("container failed twice") — no data.
// Kernel audited for OOB/LDS-overflow (none found); resubmitting unchanged.
// R3 accounting: top-5 = harness fillBuffer (80us, untouchable). Residual
// qkv + 2*attn ~= 187us vs ~50us floors -> this round: qkv LDS-write swizzle
// (8-way -> 2-way), attn LDS 43.5 -> 40KB (3 -> 4 blocks/CU), parallel rowsum.

typedef __attribute__((ext_vector_type(8))) short bf16x8;
typedef __attribute__((ext_vector_type(4))) float f32x4;
union frag_u { uint4 u4; bf16x8 h8; };

__device__ __forceinline__ float bf2f(uint32_t u) {
  union { uint32_t i; float f; } v; v.i = u << 16; return v.f;
}
__device__ __forceinline__ float bf2f_hi(uint32_t u) {
  union { uint32_t i; float f; } v; v.i = u & 0xffff0000u; return v.f;
}
__device__ __forceinline__ uint32_t f2bf(float f) {           // RNE
  union { float f; uint32_t i; } v; v.f = f;
  return (v.i + 0x7fffu + ((v.i >> 16) & 1u)) >> 16;
}
__device__ __forceinline__ void unpack8(uint4 a, float* f) {
  f[0] = bf2f(a.x); f[1] = bf2f_hi(a.x);
  f[2] = bf2f(a.y); f[3] = bf2f_hi(a.y);
  f[4] = bf2f(a.z); f[5] = bf2f_hi(a.z);
  f[6] = bf2f(a.w); f[7] = bf2f_hi(a.w);
}
__device__ __forceinline__ float ld_any(const void* p, int i, int isf32) {
  return isf32 ? ((const float*)p)[i] : bf2f(((const uint16_t*)p)[i]);
}

// LDS XOR swizzles. Both writer and reader use the same involution (rule:
// both-sides-or-neither). XOR touches only bits >=3 so 8-elem (16B) frag
// chunks stay contiguous and 16B-aligned.
#define XS_SWZ(m, k)  ((m) * 40 + ((k) ^ ((((m) >> 3) & 3) << 3)))
#define P_SWZ(r, c)   ((r) * 128 + ((c) ^ (((r) & 7) << 3)))

// -------------------------------------------------------------- detect ------
__global__ void detect_kernel(const uint16_t* __restrict__ x, int* __restrict__ flag) {
  __shared__ int bad;
  if (threadIdx.x == 0) bad = 0;
  __syncthreads();
  int hit = 0;
#pragma unroll
  for (int s = 0; s < 16; ++s) {
    uint32_t u = x[(threadIdx.x * 16 + s) * 2];
    uint32_t e = (u >> 7) & 0xffu;
    if (e == 0u || e == 255u) hit = 1;
  }
  if (hit) atomicAdd(&bad, 1);
  __syncthreads();
  if (threadIdx.x == 0) flag[0] = (bad > 0) ? 1 : 0;
}

// ---------------------------------------------------------------- prep ------
__global__ void prep_kernel(
    const int* __restrict__ flag,
    const void* __restrict__ Wq, const void* __restrict__ bq,
    const void* __restrict__ Wk, const void* __restrict__ bk,
    const void* __restrict__ Wv, const void* __restrict__ bv,
    const void* __restrict__ Wz, const void* __restrict__ bz,
    float* __restrict__ wb, float* __restrict__ wzf,
    float* __restrict__ bzf, uint16_t* __restrict__ wbf)
{
  int isf32 = flag[0];
  int t = blockIdx.x * 256 + threadIdx.x;
  if (t < 24576) {                     // wbf[n][k], n = z*32+o
    int n = t >> 8, kk = t & 255;
    int z = n >> 5, o = n & 31;
    const void* W = (z == 0) ? Wq : (z == 1) ? Wk : Wv;
    wbf[t] = (uint16_t)f2bf(ld_any(W, o * 256 + kk, isf32));
  }
  if (t < 96) {
    int z = t >> 5, o = t & 31;
    const void* bb = (z == 0) ? bq : (z == 1) ? bk : bv;
    wb[t] = ld_any(bb, o, isf32);
  }
  if (t < 8192) wzf[t] = ld_any(Wz, t, isf32);
  if (t < 256)  bzf[t] = ld_any(bz, t, isf32);
}

// ------------------------------------------------------------ qkv MFMA ------
// GEMM: out[m][n] = sum_k X[b][k][pix] * W[n][k], block = one (b, hrow) row
// of 128 pixels (m = w), N=96 (q|k|v), K=256 in 8 chunks of 32.
// R4: Xs writes were an 8-way bank conflict (stride 40 elems = 20 dwords;
// 64 consecutive-m lanes -> bank cycle period 8 -> 8 lanes/bank, 2.94x
// stall per m136). XOR k with ((m>>3)&3)<<3: within each mod-8 collision
// group the 4 swizzle values split it to 2-way (free). A-frag read applies
// the same XOR; chunks stay 16B-aligned (XOR bits >=3 only).
__global__ __launch_bounds__(256) void qkv_mfma(
    const int* __restrict__ flag, const void* __restrict__ x,
    const uint16_t* __restrict__ wbf, const float* __restrict__ wb,
    uint16_t* __restrict__ qcol, uint16_t* __restrict__ kcol,
    uint16_t* __restrict__ vcol, uint16_t* __restrict__ qrow,
    uint16_t* __restrict__ krow, uint16_t* __restrict__ vrow)
{
  __shared__ __align__(16) uint16_t Xs[128 * 40];
  int isf32 = flag[0];
  int bx = blockIdx.x;
  int b = bx >> 7, hrow = bx & 127;
  int t = threadIdx.x;
  int wv = t >> 6, L = t & 63, quad = L >> 4, l15 = L & 15;

  f32x4 acc[2][6];
#pragma unroll
  for (int mi = 0; mi < 2; ++mi)
#pragma unroll
    for (int nt = 0; nt < 6; ++nt) {
      f32x4 z0 = {0.f, 0.f, 0.f, 0.f};
      acc[mi][nt] = z0;
    }

  for (int kc = 0; kc < 8; ++kc) {
    int k0 = kc * 32;
    __syncthreads();
    // full coverage: 128 m x 32 k = 4096 elems, 16 per thread.
    if (isf32) {
      const float* xp = (const float*)x + ((size_t)b << 22)
                      + (size_t)k0 * 16384 + hrow * 128;
#pragma unroll
      for (int r = 0; r < 16; ++r) {
        int idx = r * 256 + t, k = idx >> 7, m = idx & 127;
        Xs[XS_SWZ(m, k)] = (uint16_t)f2bf(xp[(size_t)k * 16384 + m]);
      }
    } else {
      const uint16_t* xp = (const uint16_t*)x + ((size_t)b << 22)
                         + (size_t)k0 * 16384 + hrow * 128;
#pragma unroll
      for (int r = 0; r < 16; ++r) {
        int idx = r * 256 + t, k = idx >> 7, m = idx & 127;
        Xs[XS_SWZ(m, k)] = xp[(size_t)k * 16384 + m];
      }
    }
    __syncthreads();

    bf16x8 af[2];
#pragma unroll
    for (int mi = 0; mi < 2; ++mi) {
      int row = (wv * 2 + mi) * 16 + l15;
      frag_u fu;
      fu.u4 = *(const uint4*)(Xs + XS_SWZ(row, quad * 8));
      af[mi] = fu.h8;
    }
#pragma unroll
    for (int nt = 0; nt < 6; ++nt) {
      frag_u bu;
      bu.u4 = *(const uint4*)(wbf + (nt * 16 + l15) * 256 + k0 + quad * 8);
#pragma unroll
      for (int mi = 0; mi < 2; ++mi)
        acc[mi][nt] = __builtin_amdgcn_mfma_f32_16x16x32_bf16(af[mi], bu.h8, acc[mi][nt], 0, 0, 0);
    }
  }

  // epilogue: bias + store both layouts
#pragma unroll
  for (int nt = 0; nt < 6; ++nt) {
    int n = nt * 16 + l15;
    float bias = wb[n];
    int z = nt >> 1;                   // 0,1->q  2,3->k  4,5->v (uniform)
    int no = n & 31;
    uint16_t* colb = (z == 0) ? qcol : (z == 1) ? kcol : vcol;
    uint16_t* rowb = (z == 0) ? qrow : (z == 1) ? krow : vrow;
    size_t rowbase = (size_t)(b * 128 + hrow) * 4096;
#pragma unroll
    for (int mi = 0; mi < 2; ++mi) {
#pragma unroll
      for (int r = 0; r < 4; ++r) {
        int m = (wv * 2 + mi) * 16 + quad * 4 + r;    // = w coordinate
        uint16_t val = (uint16_t)f2bf(acc[mi][nt][r] + bias);
        rowb[rowbase + (size_t)m * 32 + no] = val;
        colb[(size_t)(b * 128 + m) * 4096 + hrow * 32 + no] = val;
      }
    }
  }
}

// ---------------------------------------------------------------- attn ------
// One block per (b, loc): loc=w (iscol=1, diag-masked height pass) or loc=h
// (width pass). S = Q K^T via MFMA; P = exp(S) -> LDS; rowsums; O = P V.
// R4: LDS 43520 -> 40960 B (P,vT stride 136 -> 128 + XOR swizzle) so 4
// blocks/CU fit (was 3; grid needs 4/CU -> tail round at 1/3 occupancy).
// launch_bounds(256,4) targets <=128 VGPR for 16 waves/CU; R3's bu[8] hoist
// reverted (neutral, costs 32 VGPR against this budget). Rowsum uses all 256
// threads (2/row + shfl_xor); swizzled storage row is a permutation of the
// logical row, so linear summation covers the same value set.
__global__ __launch_bounds__(256, 4) void attn_kernel(
    const uint16_t* __restrict__ q, const uint16_t* __restrict__ k,
    const uint16_t* __restrict__ v, uint16_t* __restrict__ O,
    float* __restrict__ s, int iscol)
{
  __shared__ __align__(16) uint16_t P[128 * 128];
  __shared__ __align__(16) uint16_t vT[32 * 128];

  int cid = blockIdx.x, b = cid >> 7, loc = cid & 127;
  int tid = threadIdx.x;
  const uint16_t* qc = q + (size_t)cid * 4096;
  const uint16_t* kc = k + (size_t)cid * 4096;
  const uint16_t* vc = v + (size_t)cid * 4096;

  for (int idx = tid; idx < 4096; idx += 256) {
    int ch = idx & 31, i = idx >> 5;
    vT[P_SWZ(ch, i)] = vc[idx];        // vT[ch][i], swizzled
  }

  int wv = tid >> 6, L = tid & 63, quad = L >> 4, l15 = L & 15;

  bf16x8 aq[2];
#pragma unroll
  for (int mi = 0; mi < 2; ++mi) {
    frag_u fu;
    fu.u4 = *(const uint4*)(qc + ((wv * 2 + mi) * 16 + l15) * 32 + quad * 8);
    aq[mi] = fu.h8;
  }
  for (int nt = 0; nt < 8; ++nt) {
    frag_u bu;
    bu.u4 = *(const uint4*)(kc + (nt * 16 + l15) * 32 + quad * 8);
    int col = nt * 16 + l15;
#pragma unroll
    for (int mi = 0; mi < 2; ++mi) {
      f32x4 z0 = {0.f, 0.f, 0.f, 0.f};
      f32x4 d = __builtin_amdgcn_mfma_f32_16x16x32_bf16(aq[mi], bu.h8, z0, 0, 0, 0);
      int row0 = (wv * 2 + mi) * 16 + quad * 4;
#pragma unroll
      for (int r = 0; r < 4; ++r) {
        float pe = __expf(d[r]);                 // max-free: |S| <~ 21
        if (iscol && (row0 + r) == col) pe = 0.f;
        P[P_SWZ(row0 + r, col)] = (uint16_t)f2bf(pe);
      }
    }
  }
  __syncthreads();

  {
    int row = tid >> 1, hh = tid & 1;
    float ss = 0.f;
    const uint2* pr = (const uint2*)(P + row * 128 + hh * 64);
#pragma unroll 4
    for (int j = 0; j < 16; ++j) {
      uint2 u = pr[j];
      ss += bf2f(u.x); ss += bf2f_hi(u.x);
      ss += bf2f(u.y); ss += bf2f_hi(u.y);
    }
    ss += __shfl_xor(ss, 1);
    if (hh == 0) {
      size_t sbase = (size_t)b * 16384 + (iscol ? loc : loc * 128);
      s[sbase + (size_t)row * (iscol ? 128 : 1)] = ss;
    }
  }

  f32x4 acc[2][2];
#pragma unroll
  for (int mi = 0; mi < 2; ++mi)
#pragma unroll
    for (int ni = 0; ni < 2; ++ni) {
      f32x4 z0 = {0.f, 0.f, 0.f, 0.f};
      acc[mi][ni] = z0;
    }
#pragma unroll
  for (int kk = 0; kk < 4; ++kk) {
    bf16x8 ap[2], bv2[2];
#pragma unroll
    for (int mi = 0; mi < 2; ++mi) {
      int row = (wv * 2 + mi) * 16 + l15;
      frag_u fu;
      fu.u4 = *(const uint4*)(P + P_SWZ(row, kk * 32 + quad * 8));
      ap[mi] = fu.h8;
    }
#pragma unroll
    for (int ni = 0; ni < 2; ++ni) {
      int ch = ni * 16 + l15;
      frag_u fu;
      fu.u4 = *(const uint4*)(vT + P_SWZ(ch, kk * 32 + quad * 8));
      bv2[ni] = fu.h8;
    }
#pragma unroll
    for (int mi = 0; mi < 2; ++mi)
#pragma unroll
      for (int ni = 0; ni < 2; ++ni)
        acc[mi][ni] = __builtin_amdgcn_mfma_f32_16x16x32_bf16(ap[mi], bv2[ni], acc[mi][ni], 0, 0, 0);
  }

  size_t obase = (size_t)b * 524288 + (size_t)(iscol ? loc * 32 : loc * 4096);
  int orstride = iscol ? 4096 : 32;
#pragma unroll
  for (int mi = 0; mi < 2; ++mi)
#pragma unroll
    for (int ni = 0; ni < 2; ++ni) {
      int col = ni * 16 + l15;
#pragma unroll
      for (int r = 0; r < 4; ++r) {
        int row = (wv * 2 + mi) * 16 + quad * 4 + r;
        O[obase + (size_t)row * orstride + col] = (uint16_t)f2bf(acc[mi][ni][r]);
      }
    }
}

// ------------------------------------------------------- combine + zres -----
// Stable since R3: R1 inner body (83us verified; 40 VGPR, no spills) + R2's
// XCD-coherent remap (pixblk=bid&511, cgrp=bid>>9: sibling channel-group
// blocks land on the SAME XCD since XCD = bid%8; FETCH 100.7 -> 92.2 MB).
// R2's manual 4-channel interleave regressed 83 -> 402us (VGPR<->AGPR spill
// storm, VALUBusy 90%) — do not restructure the FMA body by hand.
#define CSPLIT 4
__global__ __launch_bounds__(256) void combine_zres(
    const int* __restrict__ flag, const void* __restrict__ x,
    const uint16_t* __restrict__ Ocol, const uint16_t* __restrict__ Orow,
    const float* __restrict__ scol, const float* __restrict__ srow,
    const float* __restrict__ wzf, const float* __restrict__ bzf,
    void* __restrict__ out)
{
  int isf32 = flag[0];
  int bid = blockIdx.x;
  int pixblk = bid & 511;              // adjacent bids = different pixels
  int cgrp = bid >> 9;                 // siblings 512 apart -> same XCD L2
  int p = pixblk * 256 + threadIdx.x;
  int b = p >> 14;
  int rem = p & 16383;

  float inv = 1.0f / (scol[p] + srow[p]);
  float of[32];
  const uint4* c4 = (const uint4*)(Ocol + (size_t)p * 32);
  const uint4* r4 = (const uint4*)(Orow + (size_t)p * 32);
#pragma unroll
  for (int g = 0; g < 4; ++g) {
    float a[8], bb[8];
    unpack8(c4[g], a);
    unpack8(r4[g], bb);
#pragma unroll
    for (int j = 0; j < 8; ++j) of[g * 8 + j] = (a[j] + bb[j]) * inv;
  }

  int c0 = cgrp * (256 / CSPLIT);
  int c1 = c0 + (256 / CSPLIT);

  if (isf32) {
    const float* xp = (const float*)x + ((size_t)b << 22) + rem;
    float* op = (float*)out + ((size_t)b << 22) + rem;
#pragma unroll 2
    for (int c = c0; c < c1; ++c) {
      const float* wc = wzf + c * 32;
      float xv = xp[(size_t)c << 14];
      float a0 = 0.f, a1 = 0.f, a2 = 0.f, a3 = 0.f;
#pragma unroll
      for (int r = 0; r < 8; ++r) {
        a0 += wc[r]      * of[r];
        a1 += wc[8 + r]  * of[8 + r];
        a2 += wc[16 + r] * of[16 + r];
        a3 += wc[24 + r] * of[24 + r];
      }
      op[(size_t)c << 14] = bzf[c] + (a0 + a1) + (a2 + a3) + xv;
    }
  } else {
    const uint16_t* xp = (const uint16_t*)x + ((size_t)b << 22) + rem;
    uint16_t* op = (uint16_t*)out + ((size_t)b << 22) + rem;
#pragma unroll 2
    for (int c = c0; c < c1; ++c) {
      const float* wc = wzf + c * 32;
      float xv = bf2f(xp[(size_t)c << 14]);
      float a0 = 0.f, a1 = 0.f, a2 = 0.f, a3 = 0.f;
#pragma unroll
      for (int r = 0; r < 8; ++r) {
        a0 += wc[r]      * of[r];
        a1 += wc[8 + r]  * of[8 + r];
        a2 += wc[16 + r] * of[16 + r];
        a3 += wc[24 + r] * of[24 + r];
      }
      float acci = bzf[c] + (a0 + a1) + (a2 + a3) + xv;
      op[(size_t)c << 14] = (uint16_t)f2bf(acci);
    }
  }
}

// -------------------------------------------------------------- launch ------
extern "C" void kernel_launch(void* const* d_in, const int* in_sizes, int n_in,
                              void* d_out, int out_size, void* d_ws, size_t ws_size,
                              hipStream_t stream) {
  char* ws = (char*)d_ws;
  int*   flag = (int*)(ws);
  float* wb   = (float*)(ws + 256);
  float* wzf  = (float*)(ws + 1024);
  float* bzf  = (float*)(ws + 33792);
  uint16_t* wbf = (uint16_t*)(ws + 34816);
  uint16_t* qt = (uint16_t*)(ws + 147456);
  uint16_t* kt = qt + 4194304;
  uint16_t* vt = kt + 4194304;
  uint16_t* qr = vt + 4194304;
  uint16_t* kr = qr + 4194304;
  uint16_t* vr = kr + 4194304;
  uint16_t* Ocol = (uint16_t*)(ws + 50479104);
  uint16_t* Orow = (uint16_t*)(ws + 58867712);
  float* scol = (float*)(ws + 67256320);
  float* srow = (float*)(ws + 67780608);

  detect_kernel<<<1, 256, 0, stream>>>((const uint16_t*)d_in[0], flag);
  prep_kernel<<<96, 256, 0, stream>>>(flag, d_in[1], d_in[2], d_in[3], d_in[4],
                                      d_in[5], d_in[6], d_in[7], d_in[8],
                                      wb, wzf, bzf, wbf);
  qkv_mfma<<<1024, 256, 0, stream>>>(flag, d_in[0], wbf, wb,
                                     qt, kt, vt, qr, kr, vr);
  attn_kernel<<<1024, 256, 0, stream>>>(qt, kt, vt, Ocol, scol, 1);
  attn_kernel<<<1024, 256, 0, stream>>>(qr, kr, vr, Orow, srow, 0);
  combine_zres<<<512 * CSPLIT, 256, 0, stream>>>(flag, d_in[0], Ocol, Orow,
                                                 scol, srow, wzf, bzf, d_out);
}

// Round 6
// 340.007 us; speedup vs baseline: 1.9556x; 1.0150x over previous
//
#include <hip/hip_runtime.h>
#include <stdint.h>

// CCNet criss-cross attention block. B=8, C=256, H=W=128, CR=32.
// detect dtype -> prep weights (bf16 for MFMA, f32 for VALU) -> qkv MFMA GEMM
// (dual-layout bf16 staging) -> MFMA attention (col+row merged, 2048 blocks)
// -> combine+zres.
//
// ws layout (bytes):
//   flag @ 0
//   wb   @ 256      f32[96]   qkv bias
//   wzf  @ 1024     f32[256][32]
//   bzf  @ 33792    f32[256]
//   wbf  @ 34816    bf16[96][256]  qkv weights, n-major (49152 B)
//   qt   @ 147456   bf16 (B,W,H,32) col-major  8 MB
//   kt,vt           +8MB each
//   qr/kr/vr        +24MB..: bf16 (B,H,W,32) row-major
//   Ocol @ 50479104 bf16 (B,H,W,32) 8 MB
//   Orow @ 58867712 bf16 (B,H,W,32) 8 MB
//   scol @ 67256320 f32 (B,H,W) 512 KB
//   srow @ 67780608 f32 (B,H,W) 512 KB
//
// R5 accounting: R4's swizzle/occupancy fixes were ~neutral (348->345) ->
// qkv+attn are latency-structural, not throughput-bound. R6: qkv T14
// issue-early/write-late staging (loads for chunk k+1 issued before chunk k
// MFMAs; the old form exposed ~850cyc HBM latency per chunk since loads
// can't be hoisted above __syncthreads); attn col+row merged into one
// launch; combine pragma-unroll 4 (pragma only — R2 taught that MANUAL
// multi-accumulator restructure spills; a pragma lets regalloc serialize).

typedef __attribute__((ext_vector_type(8))) short bf16x8;
typedef __attribute__((ext_vector_type(4))) float f32x4;
union frag_u { uint4 u4; bf16x8 h8; };

__device__ __forceinline__ float bf2f(uint32_t u) {
  union { uint32_t i; float f; } v; v.i = u << 16; return v.f;
}
__device__ __forceinline__ float bf2f_hi(uint32_t u) {
  union { uint32_t i; float f; } v; v.i = u & 0xffff0000u; return v.f;
}
__device__ __forceinline__ uint32_t f2bf(float f) {           // RNE
  union { float f; uint32_t i; } v; v.f = f;
  return (v.i + 0x7fffu + ((v.i >> 16) & 1u)) >> 16;
}
__device__ __forceinline__ void unpack8(uint4 a, float* f) {
  f[0] = bf2f(a.x); f[1] = bf2f_hi(a.x);
  f[2] = bf2f(a.y); f[3] = bf2f_hi(a.y);
  f[4] = bf2f(a.z); f[5] = bf2f_hi(a.z);
  f[6] = bf2f(a.w); f[7] = bf2f_hi(a.w);
}
__device__ __forceinline__ float ld_any(const void* p, int i, int isf32) {
  return isf32 ? ((const float*)p)[i] : bf2f(((const uint16_t*)p)[i]);
}

// LDS XOR swizzles (R4, kept: harmless, mechanism-correct). XOR touches only
// bits >=3 so 8-elem (16B) frag chunks stay contiguous and 16B-aligned.
#define XS_SWZ(m, k)  ((m) * 40 + ((k) ^ ((((m) >> 3) & 3) << 3)))
#define P_SWZ(r, c)   ((r) * 128 + ((c) ^ (((r) & 7) << 3)))

// -------------------------------------------------------------- detect ------
__global__ void detect_kernel(const uint16_t* __restrict__ x, int* __restrict__ flag) {
  __shared__ int bad;
  if (threadIdx.x == 0) bad = 0;
  __syncthreads();
  int hit = 0;
#pragma unroll
  for (int s = 0; s < 16; ++s) {
    uint32_t u = x[(threadIdx.x * 16 + s) * 2];
    uint32_t e = (u >> 7) & 0xffu;
    if (e == 0u || e == 255u) hit = 1;
  }
  if (hit) atomicAdd(&bad, 1);
  __syncthreads();
  if (threadIdx.x == 0) flag[0] = (bad > 0) ? 1 : 0;
}

// ---------------------------------------------------------------- prep ------
__global__ void prep_kernel(
    const int* __restrict__ flag,
    const void* __restrict__ Wq, const void* __restrict__ bq,
    const void* __restrict__ Wk, const void* __restrict__ bk,
    const void* __restrict__ Wv, const void* __restrict__ bv,
    const void* __restrict__ Wz, const void* __restrict__ bz,
    float* __restrict__ wb, float* __restrict__ wzf,
    float* __restrict__ bzf, uint16_t* __restrict__ wbf)
{
  int isf32 = flag[0];
  int t = blockIdx.x * 256 + threadIdx.x;
  if (t < 24576) {                     // wbf[n][k], n = z*32+o
    int n = t >> 8, kk = t & 255;
    int z = n >> 5, o = n & 31;
    const void* W = (z == 0) ? Wq : (z == 1) ? Wk : Wv;
    wbf[t] = (uint16_t)f2bf(ld_any(W, o * 256 + kk, isf32));
  }
  if (t < 96) {
    int z = t >> 5, o = t & 31;
    const void* bb = (z == 0) ? bq : (z == 1) ? bk : bv;
    wb[t] = ld_any(bb, o, isf32);
  }
  if (t < 8192) wzf[t] = ld_any(Wz, t, isf32);
  if (t < 256)  bzf[t] = ld_any(bz, t, isf32);
}

// ------------------------------------------------------------ qkv MFMA ------
// GEMM: out[m][n] = sum_k X[b][k][pix] * W[n][k], block = one (b, hrow) row
// of 128 pixels (m = w), N=96 (q|k|v), K=256 in 8 chunks of 32.
// R6: T14 issue-early/write-late staging. xs[16] regs hold chunk k+1's
// loads, issued right after chunk k's second barrier (overlapping the frag
// reads + 12 MFMAs + next barrier-wait); the LDS write after the barrier
// only pays the residual latency. Values and barrier structure identical to
// R5 — pure reordering. launch_bounds(256,4) caps VGPR at 128 (est ~110)
// so 4 blocks/CU stay resident.
__global__ __launch_bounds__(256, 4) void qkv_mfma(
    const int* __restrict__ flag, const void* __restrict__ x,
    const uint16_t* __restrict__ wbf, const float* __restrict__ wb,
    uint16_t* __restrict__ qcol, uint16_t* __restrict__ kcol,
    uint16_t* __restrict__ vcol, uint16_t* __restrict__ qrow,
    uint16_t* __restrict__ krow, uint16_t* __restrict__ vrow)
{
  __shared__ __align__(16) uint16_t Xs[128 * 40];
  int isf32 = flag[0];
  int bx = blockIdx.x;
  int b = bx >> 7, hrow = bx & 127;
  int t = threadIdx.x;
  int wv = t >> 6, L = t & 63, quad = L >> 4, l15 = L & 15;
  int m_t = t & 127, kh = t >> 7;      // this thread's fixed m and k-parity

  const float*    xf = (const float*)x    + ((size_t)b << 22) + hrow * 128 + m_t;
  const uint16_t* xh = (const uint16_t*)x + ((size_t)b << 22) + hrow * 128 + m_t;

  f32x4 acc[2][6];
#pragma unroll
  for (int mi = 0; mi < 2; ++mi)
#pragma unroll
    for (int nt = 0; nt < 6; ++nt) {
      f32x4 z0 = {0.f, 0.f, 0.f, 0.f};
      acc[mi][nt] = z0;
    }

  uint32_t xs[16];                     // staged chunk (f32 bits or u16)
  auto issue = [&](int kcn) {
    if (isf32) {
#pragma unroll
      for (int r = 0; r < 16; ++r)
        xs[r] = __float_as_uint(xf[(size_t)(kcn * 32 + 2 * r + kh) * 16384]);
    } else {
#pragma unroll
      for (int r = 0; r < 16; ++r)
        xs[r] = xh[(size_t)(kcn * 32 + 2 * r + kh) * 16384];
    }
  };

  issue(0);                            // prologue: chunk 0 in flight

  for (int kc = 0; kc < 8; ++kc) {
    __syncthreads();                   // prev compute done; LDS reusable
    if (isf32) {
#pragma unroll
      for (int r = 0; r < 16; ++r)
        Xs[XS_SWZ(m_t, 2 * r + kh)] = (uint16_t)f2bf(__uint_as_float(xs[r]));
    } else {
#pragma unroll
      for (int r = 0; r < 16; ++r)
        Xs[XS_SWZ(m_t, 2 * r + kh)] = (uint16_t)xs[r];
    }
    __syncthreads();

    if (kc < 7) issue(kc + 1);         // overlap next-chunk loads with MFMAs

    int k0 = kc * 32;
    bf16x8 af[2];
#pragma unroll
    for (int mi = 0; mi < 2; ++mi) {
      int row = (wv * 2 + mi) * 16 + l15;
      frag_u fu;
      fu.u4 = *(const uint4*)(Xs + XS_SWZ(row, quad * 8));
      af[mi] = fu.h8;
    }
#pragma unroll
    for (int nt = 0; nt < 6; ++nt) {
      frag_u bu;
      bu.u4 = *(const uint4*)(wbf + (nt * 16 + l15) * 256 + k0 + quad * 8);
#pragma unroll
      for (int mi = 0; mi < 2; ++mi)
        acc[mi][nt] = __builtin_amdgcn_mfma_f32_16x16x32_bf16(af[mi], bu.h8, acc[mi][nt], 0, 0, 0);
    }
  }

  // epilogue: bias + store both layouts
#pragma unroll
  for (int nt = 0; nt < 6; ++nt) {
    int n = nt * 16 + l15;
    float bias = wb[n];
    int z = nt >> 1;                   // 0,1->q  2,3->k  4,5->v (uniform)
    int no = n & 31;
    uint16_t* colb = (z == 0) ? qcol : (z == 1) ? kcol : vcol;
    uint16_t* rowb = (z == 0) ? qrow : (z == 1) ? krow : vrow;
    size_t rowbase = (size_t)(b * 128 + hrow) * 4096;
#pragma unroll
    for (int mi = 0; mi < 2; ++mi) {
#pragma unroll
      for (int r = 0; r < 4; ++r) {
        int m = (wv * 2 + mi) * 16 + quad * 4 + r;    // = w coordinate
        uint16_t val = (uint16_t)f2bf(acc[mi][nt][r] + bias);
        rowb[rowbase + (size_t)m * 32 + no] = val;
        colb[(size_t)(b * 128 + m) * 4096 + hrow * 32 + no] = val;
      }
    }
  }
}

// ---------------------------------------------------------------- attn ------
// R6: col and row passes merged into one 2048-block launch (disjoint
// buffers; iscol = bid < 1024) — removes one launch boundary and one
// 4-blocks/CU tail. Body unchanged from R5 (passed, 345us).
__global__ __launch_bounds__(256, 4) void attn_kernel(
    const uint16_t* __restrict__ qc_, const uint16_t* __restrict__ kc_,
    const uint16_t* __restrict__ vc_, const uint16_t* __restrict__ qr_,
    const uint16_t* __restrict__ kr_, const uint16_t* __restrict__ vr_,
    uint16_t* __restrict__ Ocol, uint16_t* __restrict__ Orow,
    float* __restrict__ scol, float* __restrict__ srow)
{
  __shared__ __align__(16) uint16_t P[128 * 128];
  __shared__ __align__(16) uint16_t vT[32 * 128];

  int bidx = blockIdx.x;
  int iscol = (bidx < 1024) ? 1 : 0;
  int cid = bidx & 1023, b = cid >> 7, loc = cid & 127;
  int tid = threadIdx.x;
  const uint16_t* qc = (iscol ? qc_ : qr_) + (size_t)cid * 4096;
  const uint16_t* kc = (iscol ? kc_ : kr_) + (size_t)cid * 4096;
  const uint16_t* vc = (iscol ? vc_ : vr_) + (size_t)cid * 4096;
  uint16_t* O = iscol ? Ocol : Orow;
  float*    s = iscol ? scol : srow;

  for (int idx = tid; idx < 4096; idx += 256) {
    int ch = idx & 31, i = idx >> 5;
    vT[P_SWZ(ch, i)] = vc[idx];        // vT[ch][i], swizzled
  }

  int wv = tid >> 6, L = tid & 63, quad = L >> 4, l15 = L & 15;

  bf16x8 aq[2];
#pragma unroll
  for (int mi = 0; mi < 2; ++mi) {
    frag_u fu;
    fu.u4 = *(const uint4*)(qc + ((wv * 2 + mi) * 16 + l15) * 32 + quad * 8);
    aq[mi] = fu.h8;
  }
  for (int nt = 0; nt < 8; ++nt) {
    frag_u bu;
    bu.u4 = *(const uint4*)(kc + (nt * 16 + l15) * 32 + quad * 8);
    int col = nt * 16 + l15;
#pragma unroll
    for (int mi = 0; mi < 2; ++mi) {
      f32x4 z0 = {0.f, 0.f, 0.f, 0.f};
      f32x4 d = __builtin_amdgcn_mfma_f32_16x16x32_bf16(aq[mi], bu.h8, z0, 0, 0, 0);
      int row0 = (wv * 2 + mi) * 16 + quad * 4;
#pragma unroll
      for (int r = 0; r < 4; ++r) {
        float pe = __expf(d[r]);                 // max-free: |S| <~ 21
        if (iscol && (row0 + r) == col) pe = 0.f;
        P[P_SWZ(row0 + r, col)] = (uint16_t)f2bf(pe);
      }
    }
  }
  __syncthreads();

  {
    int row = tid >> 1, hh = tid & 1;
    float ss = 0.f;
    const uint2* pr = (const uint2*)(P + row * 128 + hh * 64);
#pragma unroll 4
    for (int j = 0; j < 16; ++j) {
      uint2 u = pr[j];
      ss += bf2f(u.x); ss += bf2f_hi(u.x);
      ss += bf2f(u.y); ss += bf2f_hi(u.y);
    }
    ss += __shfl_xor(ss, 1);
    if (hh == 0) {
      size_t sbase = (size_t)b * 16384 + (iscol ? loc : loc * 128);
      s[sbase + (size_t)row * (iscol ? 128 : 1)] = ss;
    }
  }

  f32x4 acc[2][2];
#pragma unroll
  for (int mi = 0; mi < 2; ++mi)
#pragma unroll
    for (int ni = 0; ni < 2; ++ni) {
      f32x4 z0 = {0.f, 0.f, 0.f, 0.f};
      acc[mi][ni] = z0;
    }
#pragma unroll
  for (int kk = 0; kk < 4; ++kk) {
    bf16x8 ap[2], bv2[2];
#pragma unroll
    for (int mi = 0; mi < 2; ++mi) {
      int row = (wv * 2 + mi) * 16 + l15;
      frag_u fu;
      fu.u4 = *(const uint4*)(P + P_SWZ(row, kk * 32 + quad * 8));
      ap[mi] = fu.h8;
    }
#pragma unroll
    for (int ni = 0; ni < 2; ++ni) {
      int ch = ni * 16 + l15;
      frag_u fu;
      fu.u4 = *(const uint4*)(vT + P_SWZ(ch, kk * 32 + quad * 8));
      bv2[ni] = fu.h8;
    }
#pragma unroll
    for (int mi = 0; mi < 2; ++mi)
#pragma unroll
      for (int ni = 0; ni < 2; ++ni)
        acc[mi][ni] = __builtin_amdgcn_mfma_f32_16x16x32_bf16(ap[mi], bv2[ni], acc[mi][ni], 0, 0, 0);
  }

  size_t obase = (size_t)b * 524288 + (size_t)(iscol ? loc * 32 : loc * 4096);
  int orstride = iscol ? 4096 : 32;
#pragma unroll
  for (int mi = 0; mi < 2; ++mi)
#pragma unroll
    for (int ni = 0; ni < 2; ++ni) {
      int col = ni * 16 + l15;
#pragma unroll
      for (int r = 0; r < 4; ++r) {
        int row = (wv * 2 + mi) * 16 + quad * 4 + r;
        O[obase + (size_t)row * orstride + col] = (uint16_t)f2bf(acc[mi][ni][r]);
      }
    }
}

// ------------------------------------------------------- combine + zres -----
// R1 body (83us verified) + R2's XCD-coherent remap (FETCH 100.7 -> 92.2 MB).
// R6: unroll 2 -> 4 via PRAGMA only (more loads/stores in flight; compiler
// owns live ranges — R2's manual 4x interleave spilled and must not return).
#define CSPLIT 4
__global__ __launch_bounds__(256) void combine_zres(
    const int* __restrict__ flag, const void* __restrict__ x,
    const uint16_t* __restrict__ Ocol, const uint16_t* __restrict__ Orow,
    const float* __restrict__ scol, const float* __restrict__ srow,
    const float* __restrict__ wzf, const float* __restrict__ bzf,
    void* __restrict__ out)
{
  int isf32 = flag[0];
  int bid = blockIdx.x;
  int pixblk = bid & 511;              // adjacent bids = different pixels
  int cgrp = bid >> 9;                 // siblings 512 apart -> same XCD L2
  int p = pixblk * 256 + threadIdx.x;
  int b = p >> 14;
  int rem = p & 16383;

  float inv = 1.0f / (scol[p] + srow[p]);
  float of[32];
  const uint4* c4 = (const uint4*)(Ocol + (size_t)p * 32);
  const uint4* r4 = (const uint4*)(Orow + (size_t)p * 32);
#pragma unroll
  for (int g = 0; g < 4; ++g) {
    float a[8], bb[8];
    unpack8(c4[g], a);
    unpack8(r4[g], bb);
#pragma unroll
    for (int j = 0; j < 8; ++j) of[g * 8 + j] = (a[j] + bb[j]) * inv;
  }

  int c0 = cgrp * (256 / CSPLIT);
  int c1 = c0 + (256 / CSPLIT);

  if (isf32) {
    const float* xp = (const float*)x + ((size_t)b << 22) + rem;
    float* op = (float*)out + ((size_t)b << 22) + rem;
#pragma unroll 4
    for (int c = c0; c < c1; ++c) {
      const float* wc = wzf + c * 32;
      float xv = xp[(size_t)c << 14];
      float a0 = 0.f, a1 = 0.f, a2 = 0.f, a3 = 0.f;
#pragma unroll
      for (int r = 0; r < 8; ++r) {
        a0 += wc[r]      * of[r];
        a1 += wc[8 + r]  * of[8 + r];
        a2 += wc[16 + r] * of[16 + r];
        a3 += wc[24 + r] * of[24 + r];
      }
      op[(size_t)c << 14] = bzf[c] + (a0 + a1) + (a2 + a3) + xv;
    }
  } else {
    const uint16_t* xp = (const uint16_t*)x + ((size_t)b << 22) + rem;
    uint16_t* op = (uint16_t*)out + ((size_t)b << 22) + rem;
#pragma unroll 4
    for (int c = c0; c < c1; ++c) {
      const float* wc = wzf + c * 32;
      float xv = bf2f(xp[(size_t)c << 14]);
      float a0 = 0.f, a1 = 0.f, a2 = 0.f, a3 = 0.f;
#pragma unroll
      for (int r = 0; r < 8; ++r) {
        a0 += wc[r]      * of[r];
        a1 += wc[8 + r]  * of[8 + r];
        a2 += wc[16 + r] * of[16 + r];
        a3 += wc[24 + r] * of[24 + r];
      }
      float acci = bzf[c] + (a0 + a1) + (a2 + a3) + xv;
      op[(size_t)c << 14] = (uint16_t)f2bf(acci);
    }
  }
}

// -------------------------------------------------------------- launch ------
extern "C" void kernel_launch(void* const* d_in, const int* in_sizes, int n_in,
                              void* d_out, int out_size, void* d_ws, size_t ws_size,
                              hipStream_t stream) {
  char* ws = (char*)d_ws;
  int*   flag = (int*)(ws);
  float* wb   = (float*)(ws + 256);
  float* wzf  = (float*)(ws + 1024);
  float* bzf  = (float*)(ws + 33792);
  uint16_t* wbf = (uint16_t*)(ws + 34816);
  uint16_t* qt = (uint16_t*)(ws + 147456);
  uint16_t* kt = qt + 4194304;
  uint16_t* vt = kt + 4194304;
  uint16_t* qr = vt + 4194304;
  uint16_t* kr = qr + 4194304;
  uint16_t* vr = kr + 4194304;
  uint16_t* Ocol = (uint16_t*)(ws + 50479104);
  uint16_t* Orow = (uint16_t*)(ws + 58867712);
  float* scol = (float*)(ws + 67256320);
  float* srow = (float*)(ws + 67780608);

  detect_kernel<<<1, 256, 0, stream>>>((const uint16_t*)d_in[0], flag);
  prep_kernel<<<96, 256, 0, stream>>>(flag, d_in[1], d_in[2], d_in[3], d_in[4],
                                      d_in[5], d_in[6], d_in[7], d_in[8],
                                      wb, wzf, bzf, wbf);
  qkv_mfma<<<1024, 256, 0, stream>>>(flag, d_in[0], wbf, wb,
                                     qt, kt, vt, qr, kr, vr);
  attn_kernel<<<2048, 256, 0, stream>>>(qt, kt, vt, qr, kr, vr,
                                        Ocol, Orow, scol, srow);
  combine_zres<<<512 * CSPLIT, 256, 0, stream>>>(flag, d_in[0], Ocol, Orow,
                                                 scol, srow, wzf, bzf, d_out);
}